// Round 5
// baseline (577.244 us; speedup 1.0000x reference)
//
#include <hip/hip_runtime.h>
#include <hip/hip_bf16.h>

#define DIM 32
#define RPB 128            // receivers per bucket (r_local fits 7 bits)
#define NBMAX 1024         // supports N <= 131072
#define QPAD 36            // sQ row stride (ushorts) — LDS bank spread
#define APAD 33            // acc row stride (floats) — LDS bank spread

// ---------------- bf16 <-> fp32 helpers ------------------------------------
__device__ __forceinline__ float b2f(ushort h) {
    union { float f; unsigned u; } u; u.u = ((unsigned)h) << 16; return u.f;
}
__device__ __forceinline__ ushort f2b(float f) {
    union { __hip_bfloat16 b; ushort u; } c; c.b = __float2bfloat16(f); return c.u;
}

// ---------------------------------------------------------------------------
// Probe: flags[0] = idx layout (0=int32, 1=int64 low-words), flags[1] = bf16?
// ---------------------------------------------------------------------------
__global__ void probe_kernel(const ushort* __restrict__ xh,
                             const int* __restrict__ idx,
                             int* __restrict__ flags) {
    if (threadIdx.x == 0 && blockIdx.x == 0) {
        int cnt = 0;
        for (int i = 0; i < 128; ++i) {
            int e = (xh[2 * i] >> 7) & 0xFF;
            if (e >= 100 && e <= 135) ++cnt;
        }
        flags[1] = (cnt >= 100) ? 1 : 0;
        int odd_nonzero = 0;
        for (int i = 1; i < 256; i += 2) odd_nonzero += (idx[i] != 0) ? 1 : 0;
        flags[0] = (odd_nonzero == 0) ? 1 : 0;
    }
}

__device__ __forceinline__ int load_idx(const int* __restrict__ idx, size_t pos,
                                        int mode, int n) {
    int v = mode ? idx[2 * pos] : idx[pos];
    return v < 0 ? 0 : (v >= n ? n - 1 : v);
}

__device__ __forceinline__ float load_f(const void* p, size_t i, int bf) {
    return bf ? b2f(((const ushort*)p)[i]) : ((const float*)p)[i];
}

// ---------------------------------------------------------------------------
// K1: Q|K|V = x @ {Wq,Wk,Wv}, fp32 accumulate, stored bf16.
// ---------------------------------------------------------------------------
__global__ void __launch_bounds__(256)
qkv_kernel(const void* __restrict__ x_, const void* __restrict__ Wq_,
           const void* __restrict__ Wk_, const void* __restrict__ Wv_,
           int N, ushort* __restrict__ Q, ushort* __restrict__ K,
           ushort* __restrict__ V, const int* __restrict__ flags) {
    const int bf = flags[1];
    __shared__ float sW[3][DIM * DIM];
    __shared__ float sx[8][DIM];

    const int tid = threadIdx.x;
    for (int i = tid; i < DIM * DIM; i += 256) {
        sW[0][i] = load_f(Wq_, i, bf);
        sW[1][i] = load_f(Wk_, i, bf);
        sW[2][i] = load_f(Wv_, i, bf);
    }
    const int lr  = tid >> 5;
    const int d   = tid & 31;
    const int row = blockIdx.x * 8 + lr;
    if (row < N) sx[lr][d] = load_f(x_, (size_t)row * DIM + d, bf);
    __syncthreads();
    if (row >= N) return;

    float aq = 0.f, ak = 0.f, av = 0.f;
#pragma unroll
    for (int k = 0; k < DIM; ++k) {
        const float xk = sx[lr][k];
        aq += xk * sW[0][k * DIM + d];
        ak += xk * sW[1][k * DIM + d];
        av += xk * sW[2][k * DIM + d];
    }
    const size_t o = (size_t)row * DIM + d;
    Q[o] = f2b(aq); K[o] = f2b(ak); V[o] = f2b(av);
}

// ---------------------------------------------------------------------------
// K2: per-bucket edge histogram. Each block: LDS hist over <=16384 edges,
// then one global atomicAdd per nonzero bucket.
// ---------------------------------------------------------------------------
__global__ void __launch_bounds__(256)
bin_count_kernel(const int* __restrict__ idx, int E, int N, int nb,
                 int* __restrict__ bcount, const int* __restrict__ flags) {
    const int mode = flags[0];
    __shared__ int h[NBMAX];
    const int tid = threadIdx.x;
    for (int i = tid; i < nb; i += 256) h[i] = 0;
    __syncthreads();
    const int base_e = blockIdx.x * 256 * 64;
#pragma unroll 4
    for (int k = 0; k < 64; ++k) {
        const int e = base_e + k * 256 + tid;
        if (e < E) {
            const int r = load_idx(idx, (size_t)E + e, mode, N);
            atomicAdd(&h[r >> 7], 1);
        }
    }
    __syncthreads();
    for (int i = tid; i < nb; i += 256)
        if (h[i]) atomicAdd(&bcount[i], h[i]);
}

// ---------------------------------------------------------------------------
// K3: exclusive scan of bcount[nb] (nb ~ 782). One wave, chunked.
// Also initializes bcursor = bbase.
// ---------------------------------------------------------------------------
__global__ void __launch_bounds__(64)
bucket_scan_kernel(const int* __restrict__ bcount, int* __restrict__ bbase,
                   int* __restrict__ bcursor, int nb) {
    __shared__ int sRun;
    const int tid = threadIdx.x;
    if (tid == 0) sRun = 0;
    __syncthreads();
    for (int start = 0; start < nb; start += 64) {
        const int ii = start + tid;
        const int v = (ii < nb) ? bcount[ii] : 0;
        int x = v;
#pragma unroll
        for (int off = 1; off < 64; off <<= 1) {
            int t2 = __shfl_up(x, off);
            if (tid >= off) x += t2;
        }
        const int run = sRun;
        __syncthreads();
        if (ii < nb) { const int ex = run + x - v; bbase[ii] = ex; bcursor[ii] = ex; }
        if (tid == 63) sRun = run + x;
        __syncthreads();
    }
}

// ---------------------------------------------------------------------------
// K4: place packed edges (s | r_local<<17) into bucket regions.
// Per-block LDS hist -> one global reservation per bucket -> LDS-cursor place.
// Per-block per-bucket chunks are contiguous ints -> good write locality.
// ---------------------------------------------------------------------------
__global__ void __launch_bounds__(256)
bin_place_kernel(const int* __restrict__ idx, int E, int N, int nb,
                 int* __restrict__ bcursor, int* __restrict__ bedges,
                 const int* __restrict__ flags) {
    const int mode = flags[0];
    __shared__ int h[NBMAX];
    __shared__ int goff[NBMAX];
    const int tid = threadIdx.x;
    for (int i = tid; i < nb; i += 256) h[i] = 0;
    __syncthreads();
    const int base_e = blockIdx.x * 256 * 64;
#pragma unroll 4
    for (int k = 0; k < 64; ++k) {
        const int e = base_e + k * 256 + tid;
        if (e < E) {
            const int r = load_idx(idx, (size_t)E + e, mode, N);
            atomicAdd(&h[r >> 7], 1);
        }
    }
    __syncthreads();
    for (int i = tid; i < nb; i += 256)
        goff[i] = h[i] ? atomicAdd(&bcursor[i], h[i]) : 0;
    __syncthreads();
    for (int i = tid; i < nb; i += 256) h[i] = 0;
    __syncthreads();
#pragma unroll 4
    for (int k = 0; k < 64; ++k) {
        const int e = base_e + k * 256 + tid;
        if (e < E) {
            const int r = load_idx(idx, (size_t)E + e, mode, N);
            const int s = load_idx(idx, (size_t)e, mode, N);
            const int b = r >> 7;
            const int lp = atomicAdd(&h[b], 1);
            bedges[goff[b] + lp] = s | ((r & 127) << 17);
        }
    }
}

// ---------------------------------------------------------------------------
// K5: one block per bucket. Q rows staged in LDS; acc/Z in LDS (atomics);
// fused normalize + @Wo + residual epilogue. Zero global atomics.
// ---------------------------------------------------------------------------
__global__ void __launch_bounds__(256)
agg_kernel(const ushort* __restrict__ Q, const ushort* __restrict__ K,
           const ushort* __restrict__ V, const int* __restrict__ bedges,
           const int* __restrict__ bbase, const int* __restrict__ bcount,
           const void* __restrict__ x_, const void* __restrict__ Wo_,
           int N, float* __restrict__ out, const int* __restrict__ flags) {
    const int bf = flags[1];
    __shared__ float accS[RPB * APAD];   // 16.9 KB
    __shared__ float Zs[RPB];
    __shared__ float sWo[DIM * DIM];     // 4 KB
    __shared__ ushort sQ[RPB * QPAD];    // 9.2 KB

    const int tid = threadIdx.x;
    const int b  = blockIdx.x;
    const int r0 = b * RPB;
    const int nr = min(RPB, N - r0);

    for (int i = tid; i < DIM * DIM; i += 256) sWo[i] = load_f(Wo_, i, bf);
    for (int i = tid; i < RPB * APAD; i += 256) accS[i] = 0.f;
    for (int i = tid; i < RPB; i += 256) Zs[i] = 0.f;
    // stage Q rows (ushort4 = 8B chunks)
    for (int i = tid; i < nr * 8; i += 256) {
        const int rr = i >> 3, cc = i & 7;
        *(ushort4*)(sQ + rr * QPAD + cc * 4) =
            ((const ushort4*)(Q + (size_t)r0 * DIM))[i];
    }
    __syncthreads();

    const int cnt = bcount[b];
    const int s0  = bbase[b];
    const int w    = tid >> 6;
    const int lane = tid & 63;
    const int i8   = lane >> 3;   // edge sub-slot 0..7
    const int j    = lane & 7;    // channel group 0..7

    for (int c0 = w * 8; c0 < cnt; c0 += 32) {
        const int c  = c0 + i8;
        const bool ok = (c < cnt);
        const int  e  = bedges[s0 + (ok ? c : cnt - 1)];
        const int  s  = e & 0x1FFFF;
        const int  rl = (e >> 17) & 127;

        const ushort4 qh = *(const ushort4*)(sQ + rl * QPAD + j * 4);
        const ushort4 kh = *(const ushort4*)(K + (size_t)s * DIM + j * 4);
        float p = b2f(qh.x) * b2f(kh.x) + b2f(qh.y) * b2f(kh.y) +
                  b2f(qh.z) * b2f(kh.z) + b2f(qh.w) * b2f(kh.w);
        p += __shfl_xor(p, 1);
        p += __shfl_xor(p, 2);
        p += __shfl_xor(p, 4);

        float sc = p * 0.17677669529663687f;   // 1/sqrt(32)
        sc = fminf(fmaxf(sc, -60.f), 60.f);
        const float a = ok ? __expf(sc) : 0.f;

        const ushort4 vh = *(const ushort4*)(V + (size_t)s * DIM + j * 4);
        float* ap = accS + rl * APAD + j * 4;
        atomicAdd(ap + 0, a * b2f(vh.x));
        atomicAdd(ap + 1, a * b2f(vh.y));
        atomicAdd(ap + 2, a * b2f(vh.z));
        atomicAdd(ap + 3, a * b2f(vh.w));
        if (j == 0) atomicAdd(&Zs[rl], a);
    }
    __syncthreads();

    // epilogue: 256 threads = 8 rows x 32 cols, 16 iterations covers 128 rows
    const int lr = tid >> 5;
    const int d  = tid & 31;
#pragma unroll 4
    for (int it = 0; it < RPB / 8; ++it) {
        const int rl = it * 8 + lr;
        if (rl < nr) {
            const float inv = 1.f / (Zs[rl] + 1e-6f);
            float o = 0.f;
#pragma unroll
            for (int k = 0; k < DIM; ++k) o += accS[rl * APAD + k] * sWo[k * DIM + d];
            const size_t oi = (size_t)(r0 + rl) * DIM + d;
            out[oi] = load_f(x_, oi, bf) + inv * o;
        }
    }
}

// ---------------------------------------------------------------------------
extern "C" void kernel_launch(void* const* d_in, const int* in_sizes, int n_in,
                              void* d_out, int out_size, void* d_ws, size_t ws_size,
                              hipStream_t stream) {
    const void* x   = d_in[0];
    const int*  idx = (const int*)d_in[1];
    const void* Wq  = d_in[2];
    const void* Wk  = d_in[3];
    const void* Wv  = d_in[4];
    const void* Wo  = d_in[5];
    float* out = (float*)d_out;           // fp32 reference output

    const int N = in_sizes[0] / DIM;      // 100000
    const int E = in_sizes[1] / 2;        // 1600000
    const int nb = (N + RPB - 1) / RPB;   // 782 buckets
    const size_t N32 = (size_t)N * DIM;

    // Workspace (~26 MB): Q|K|V bf16, bedges int[E], bcount|bbase|bcursor, flags
    ushort* Q      = (ushort*)d_ws;
    ushort* K      = Q + N32;
    ushort* V      = K + N32;
    int* bedges    = (int*)(V + N32);
    int* bcount    = bedges + E;
    int* bbase     = bcount + NBMAX;
    int* bcursor   = bbase + NBMAX;
    int* flags     = bcursor + NBMAX;

    probe_kernel<<<1, 64, 0, stream>>>((const ushort*)x, idx, flags);
    hipMemsetAsync(bcount, 0, NBMAX * sizeof(int), stream);

    qkv_kernel<<<(N + 7) / 8, 256, 0, stream>>>(x, Wq, Wk, Wv, N, Q, K, V, flags);

    const int bin_blocks = (E + 256 * 64 - 1) / (256 * 64);   // 98
    bin_count_kernel<<<bin_blocks, 256, 0, stream>>>(idx, E, N, nb, bcount, flags);
    bucket_scan_kernel<<<1, 64, 0, stream>>>(bcount, bbase, bcursor, nb);
    bin_place_kernel<<<bin_blocks, 256, 0, stream>>>(idx, E, N, nb, bcursor,
                                                     bedges, flags);

    agg_kernel<<<nb, 256, 0, stream>>>(Q, K, V, bedges, bbase, bcount,
                                       x, Wo, N, out, flags);
}

// Round 6
// 290.863 us; speedup vs baseline: 1.9846x; 1.9846x over previous
//
#include <hip/hip_runtime.h>
#include <hip/hip_bf16.h>

#define DIM 32
#define RPB 128            // receivers per bucket (r_local fits 7 bits)
#define NBMAX 1024         // supports N <= 131072
#define SORT_CAP 6144      // LDS edge stage cap; E/nb ~= 2048, sd ~45 -> safe

// ---------------- bf16 <-> fp32 helpers ------------------------------------
__device__ __forceinline__ float b2f(ushort h) {
    union { float f; unsigned u; } u; u.u = ((unsigned)h) << 16; return u.f;
}
__device__ __forceinline__ ushort f2b(float f) {
    union { __hip_bfloat16 b; ushort u; } c; c.b = __float2bfloat16(f); return c.u;
}

// ---------------------------------------------------------------------------
// Probe: flags[0] = idx layout (0=int32, 1=int64 low-words), flags[1] = bf16?
// ---------------------------------------------------------------------------
__global__ void probe_kernel(const ushort* __restrict__ xh,
                             const int* __restrict__ idx,
                             int* __restrict__ flags) {
    if (threadIdx.x == 0 && blockIdx.x == 0) {
        int cnt = 0;
        for (int i = 0; i < 128; ++i) {
            int e = (xh[2 * i] >> 7) & 0xFF;
            if (e >= 100 && e <= 135) ++cnt;
        }
        flags[1] = (cnt >= 100) ? 1 : 0;
        int odd_nonzero = 0;
        for (int i = 1; i < 256; i += 2) odd_nonzero += (idx[i] != 0) ? 1 : 0;
        flags[0] = (odd_nonzero == 0) ? 1 : 0;
    }
}

__device__ __forceinline__ int load_idx(const int* __restrict__ idx, size_t pos,
                                        int mode, int n) {
    int v = mode ? idx[2 * pos] : idx[pos];
    return v < 0 ? 0 : (v >= n ? n - 1 : v);
}

__device__ __forceinline__ float load_f(const void* p, size_t i, int bf) {
    return bf ? b2f(((const ushort*)p)[i]) : ((const float*)p)[i];
}

// ---------------------------------------------------------------------------
// K1: Q|K|V = x @ {Wq,Wk,Wv}, fp32 accumulate, stored bf16.
// ---------------------------------------------------------------------------
__global__ void __launch_bounds__(256)
qkv_kernel(const void* __restrict__ x_, const void* __restrict__ Wq_,
           const void* __restrict__ Wk_, const void* __restrict__ Wv_,
           int N, ushort* __restrict__ Q, ushort* __restrict__ K,
           ushort* __restrict__ V, const int* __restrict__ flags) {
    const int bf = flags[1];
    __shared__ float sW[3][DIM * DIM];
    __shared__ float sx[8][DIM];

    const int tid = threadIdx.x;
    for (int i = tid; i < DIM * DIM; i += 256) {
        sW[0][i] = load_f(Wq_, i, bf);
        sW[1][i] = load_f(Wk_, i, bf);
        sW[2][i] = load_f(Wv_, i, bf);
    }
    const int lr  = tid >> 5;
    const int d   = tid & 31;
    const int row = blockIdx.x * 8 + lr;
    if (row < N) sx[lr][d] = load_f(x_, (size_t)row * DIM + d, bf);
    __syncthreads();
    if (row >= N) return;

    float aq = 0.f, ak = 0.f, av = 0.f;
#pragma unroll
    for (int k = 0; k < DIM; ++k) {
        const float xk = sx[lr][k];
        aq += xk * sW[0][k * DIM + d];
        ak += xk * sW[1][k * DIM + d];
        av += xk * sW[2][k * DIM + d];
    }
    const size_t o = (size_t)row * DIM + d;
    Q[o] = f2b(aq); K[o] = f2b(ak); V[o] = f2b(av);
}

// ---------------------------------------------------------------------------
// K2: per-bucket edge histogram (LDS hist per block, few global atomics).
// ---------------------------------------------------------------------------
__global__ void __launch_bounds__(256)
bin_count_kernel(const int* __restrict__ idx, int E, int N, int nb,
                 int* __restrict__ bcount, const int* __restrict__ flags) {
    const int mode = flags[0];
    __shared__ int h[NBMAX];
    const int tid = threadIdx.x;
    for (int i = tid; i < nb; i += 256) h[i] = 0;
    __syncthreads();
    const int base_e = blockIdx.x * 256 * 64;
#pragma unroll 4
    for (int k = 0; k < 64; ++k) {
        const int e = base_e + k * 256 + tid;
        if (e < E) {
            const int r = load_idx(idx, (size_t)E + e, mode, N);
            atomicAdd(&h[r >> 7], 1);
        }
    }
    __syncthreads();
    for (int i = tid; i < nb; i += 256)
        if (h[i]) atomicAdd(&bcount[i], h[i]);
}

// ---------------------------------------------------------------------------
// K3: exclusive scan of bcount[nb] (nb ~ 782). One wave, chunked.
// ---------------------------------------------------------------------------
__global__ void __launch_bounds__(64)
bucket_scan_kernel(const int* __restrict__ bcount, int* __restrict__ bbase,
                   int* __restrict__ bcursor, int nb) {
    __shared__ int sRun;
    const int tid = threadIdx.x;
    if (tid == 0) sRun = 0;
    __syncthreads();
    for (int start = 0; start < nb; start += 64) {
        const int ii = start + tid;
        const int v = (ii < nb) ? bcount[ii] : 0;
        int x = v;
#pragma unroll
        for (int off = 1; off < 64; off <<= 1) {
            int t2 = __shfl_up(x, off);
            if (tid >= off) x += t2;
        }
        const int run = sRun;
        __syncthreads();
        if (ii < nb) { const int ex = run + x - v; bbase[ii] = ex; bcursor[ii] = ex; }
        if (tid == 63) sRun = run + x;
        __syncthreads();
    }
}

// ---------------------------------------------------------------------------
// K4: place packed edges (s | r_local<<17) into bucket regions.
// ---------------------------------------------------------------------------
__global__ void __launch_bounds__(256)
bin_place_kernel(const int* __restrict__ idx, int E, int N, int nb,
                 int* __restrict__ bcursor, int* __restrict__ bedges,
                 const int* __restrict__ flags) {
    const int mode = flags[0];
    __shared__ int h[NBMAX];
    __shared__ int goff[NBMAX];
    const int tid = threadIdx.x;
    for (int i = tid; i < nb; i += 256) h[i] = 0;
    __syncthreads();
    const int base_e = blockIdx.x * 256 * 64;
#pragma unroll 4
    for (int k = 0; k < 64; ++k) {
        const int e = base_e + k * 256 + tid;
        if (e < E) {
            const int r = load_idx(idx, (size_t)E + e, mode, N);
            atomicAdd(&h[r >> 7], 1);
        }
    }
    __syncthreads();
    for (int i = tid; i < nb; i += 256)
        goff[i] = h[i] ? atomicAdd(&bcursor[i], h[i]) : 0;
    __syncthreads();
    for (int i = tid; i < nb; i += 256) h[i] = 0;
    __syncthreads();
#pragma unroll 4
    for (int k = 0; k < 64; ++k) {
        const int e = base_e + k * 256 + tid;
        if (e < E) {
            const int r = load_idx(idx, (size_t)E + e, mode, N);
            const int s = load_idx(idx, (size_t)e, mode, N);
            const int b = r >> 7;
            const int lp = atomicAdd(&h[b], 1);
            bedges[goff[b] + lp] = s | ((r & 127) << 17);
        }
    }
}

// ---------------------------------------------------------------------------
// K5: per-bucket LDS counting sort -> in-place receiver-sorted bedges
// (sender id only) + per-receiver rbase/rcount. One block per bucket.
// ---------------------------------------------------------------------------
__global__ void __launch_bounds__(256)
bucket_sort_kernel(const int* __restrict__ bcount, const int* __restrict__ bbase,
                   int* __restrict__ bedges, int* __restrict__ rbase,
                   int* __restrict__ rcount, int N) {
    __shared__ int eL[SORT_CAP];
    __shared__ int h[RPB];
    __shared__ int off[RPB];
    __shared__ int cur[RPB];

    const int tid = threadIdx.x;
    const int b   = blockIdx.x;
    const int s0  = bbase[b];
    int cnt = bcount[b];
    if (cnt > SORT_CAP) cnt = SORT_CAP;   // statistically unreachable
    const int r0 = b * RPB;
    const int nr = min(RPB, N - r0);

    for (int i = tid; i < RPB; i += 256) h[i] = 0;
    __syncthreads();
    for (int i = tid; i < cnt; i += 256) {
        const int e = bedges[s0 + i];
        eL[i] = e;
        atomicAdd(&h[(e >> 17) & 127], 1);
    }
    __syncthreads();
    if (tid == 0) {
        int a = 0;
        for (int k = 0; k < RPB; ++k) { off[k] = a; a += h[k]; }
    }
    __syncthreads();
    for (int i = tid; i < nr; i += 256) {
        rbase[r0 + i]  = s0 + off[i];
        rcount[r0 + i] = h[i];
        cur[i] = off[i];
    }
    __syncthreads();
    for (int i = tid; i < cnt; i += 256) {
        const int e  = eL[i];
        const int rl = (e >> 17) & 127;
        const int p  = atomicAdd(&cur[rl], 1);
        bedges[s0 + p] = e & 0x1FFFF;
    }
}

// ---------------------------------------------------------------------------
// K6: wave-per-receiver aggregation (round-4 structure, high occupancy).
// 64 lanes = 8 edges x 8 channel-groups. Fused normalize + @Wo + residual.
// ---------------------------------------------------------------------------
__global__ void __launch_bounds__(256)
agg_kernel(const ushort* __restrict__ Q, const ushort* __restrict__ K,
           const ushort* __restrict__ V, const int* __restrict__ slots,
           const int* __restrict__ rbase, const int* __restrict__ rcount,
           const void* __restrict__ x_, const void* __restrict__ Wo_,
           int N, float* __restrict__ out, const int* __restrict__ flags) {
    const int bf = flags[1];
    __shared__ float sWo[DIM * DIM];
    __shared__ float shH[4][DIM];

    const int tid = threadIdx.x;
    for (int i2 = tid; i2 < DIM * DIM; i2 += 256) sWo[i2] = load_f(Wo_, i2, bf);

    const int w    = tid >> 6;
    const int lane = tid & 63;
    const int i    = lane >> 3;    // edge sub-slot 0..7
    const int j    = lane & 7;     // channel group 0..7
    const int r    = blockIdx.x * 4 + w;

    float ax = 0.f, ay = 0.f, azc = 0.f, aw = 0.f;
    float zsum = 0.f;
    float q0 = 0.f, q1 = 0.f, q2 = 0.f, q3 = 0.f;
    int deg = 0, b0 = 0;

    if (r < N) {
        deg = rcount[r];
        b0  = rbase[r];
        const ushort4 qh = *(const ushort4*)(Q + (size_t)r * DIM + j * 4);
        q0 = b2f(qh.x); q1 = b2f(qh.y); q2 = b2f(qh.z); q3 = b2f(qh.w);
    }

    const int chunks = (deg + 7) >> 3;
    for (int cc = 0; cc < chunks; ++cc) {
        const int c   = cc * 8 + i;
        const bool ok = (c < deg);
        const int  s  = slots[b0 + (ok ? c : deg - 1)];

        const ushort4 kh = *(const ushort4*)(K + (size_t)s * DIM + j * 4);
        float p = q0 * b2f(kh.x) + q1 * b2f(kh.y) + q2 * b2f(kh.z) + q3 * b2f(kh.w);
        p += __shfl_xor(p, 1);
        p += __shfl_xor(p, 2);
        p += __shfl_xor(p, 4);

        float sc = p * 0.17677669529663687f;   // 1/sqrt(32)
        sc = fminf(fmaxf(sc, -60.f), 60.f);
        const float a = ok ? __expf(sc) : 0.f;

        const ushort4 vh = *(const ushort4*)(V + (size_t)s * DIM + j * 4);
        ax  += a * b2f(vh.x); ay += a * b2f(vh.y);
        azc += a * b2f(vh.z); aw += a * b2f(vh.w);
        zsum += a;
    }

#pragma unroll
    for (int off = 8; off < 64; off <<= 1) {
        ax   += __shfl_xor(ax,  off);
        ay   += __shfl_xor(ay,  off);
        azc  += __shfl_xor(azc, off);
        aw   += __shfl_xor(aw,  off);
        zsum += __shfl_xor(zsum, off);
    }

    if (r < N && i == 0) {
        shH[w][j * 4 + 0] = ax;
        shH[w][j * 4 + 1] = ay;
        shH[w][j * 4 + 2] = azc;
        shH[w][j * 4 + 3] = aw;
    }
    __syncthreads();

    if (r < N && lane < DIM) {
        const float inv = 1.f / (zsum + 1e-6f);
        float o = 0.f;
#pragma unroll
        for (int k = 0; k < DIM; ++k) o += shH[w][k] * sWo[k * DIM + lane];
        const size_t oi = (size_t)r * DIM + lane;
        out[oi] = load_f(x_, oi, bf) + inv * o;
    }
}

// ---------------------------------------------------------------------------
extern "C" void kernel_launch(void* const* d_in, const int* in_sizes, int n_in,
                              void* d_out, int out_size, void* d_ws, size_t ws_size,
                              hipStream_t stream) {
    const void* x   = d_in[0];
    const int*  idx = (const int*)d_in[1];
    const void* Wq  = d_in[2];
    const void* Wk  = d_in[3];
    const void* Wv  = d_in[4];
    const void* Wo  = d_in[5];
    float* out = (float*)d_out;           // fp32 reference output

    const int N = in_sizes[0] / DIM;      // 100000
    const int E = in_sizes[1] / 2;        // 1600000
    const int nb = (N + RPB - 1) / RPB;   // 782 buckets
    const size_t N32 = (size_t)N * DIM;

    // Workspace (~26.6 MB): Q|K|V bf16, bedges int[E], buckets, rbase|rcount
    ushort* Q      = (ushort*)d_ws;
    ushort* K      = Q + N32;
    ushort* V      = K + N32;
    int* bedges    = (int*)(V + N32);
    int* bcount    = bedges + E;
    int* bbase     = bcount + NBMAX;
    int* bcursor   = bbase + NBMAX;
    int* rbase     = bcursor + NBMAX;
    int* rcount    = rbase + N;
    int* flags     = rcount + N;

    probe_kernel<<<1, 64, 0, stream>>>((const ushort*)x, idx, flags);
    hipMemsetAsync(bcount, 0, NBMAX * sizeof(int), stream);

    qkv_kernel<<<(N + 7) / 8, 256, 0, stream>>>(x, Wq, Wk, Wv, N, Q, K, V, flags);

    const int bin_blocks = (E + 256 * 64 - 1) / (256 * 64);   // 98
    bin_count_kernel<<<bin_blocks, 256, 0, stream>>>(idx, E, N, nb, bcount, flags);
    bucket_scan_kernel<<<1, 64, 0, stream>>>(bcount, bbase, bcursor, nb);
    bin_place_kernel<<<bin_blocks, 256, 0, stream>>>(idx, E, N, nb, bcursor,
                                                     bedges, flags);
    bucket_sort_kernel<<<nb, 256, 0, stream>>>(bcount, bbase, bedges,
                                               rbase, rcount, N);

    agg_kernel<<<(N + 3) / 4, 256, 0, stream>>>(Q, K, V, bedges, rbase, rcount,
                                                x, Wo, N, out, flags);
}

// Round 7
// 278.964 us; speedup vs baseline: 2.0692x; 1.0427x over previous
//
#include <hip/hip_runtime.h>
#include <hip/hip_bf16.h>

#define DIM 32
#define RPB 128            // receivers per bucket (r_local fits 7 bits)
#define NBMAX 1024         // supports N <= 131072
#define SORT_CAP 6144      // LDS edge stage cap; E/nb ~= 2048, sd ~45 -> safe
#define EPB (256 * 64)     // edges per binning block

// ---------------- bf16 <-> fp32 helpers ------------------------------------
__device__ __forceinline__ float b2f(ushort h) {
    union { float f; unsigned u; } u; u.u = ((unsigned)h) << 16; return u.f;
}
__device__ __forceinline__ ushort f2b(float f) {
    union { __hip_bfloat16 b; ushort u; } c; c.b = __float2bfloat16(f); return c.u;
}

// ---------------------------------------------------------------------------
// Probe: flags[0] = idx layout (0=int32, 1=int64 low-words), flags[1] = bf16?
// ---------------------------------------------------------------------------
__global__ void probe_kernel(const ushort* __restrict__ xh,
                             const int* __restrict__ idx,
                             int* __restrict__ flags) {
    if (threadIdx.x == 0 && blockIdx.x == 0) {
        int cnt = 0;
        for (int i = 0; i < 128; ++i) {
            int e = (xh[2 * i] >> 7) & 0xFF;
            if (e >= 100 && e <= 135) ++cnt;
        }
        flags[1] = (cnt >= 100) ? 1 : 0;
        int odd_nonzero = 0;
        for (int i = 1; i < 256; i += 2) odd_nonzero += (idx[i] != 0) ? 1 : 0;
        flags[0] = (odd_nonzero == 0) ? 1 : 0;
    }
}

__device__ __forceinline__ int load_idx(const int* __restrict__ idx, size_t pos,
                                        int mode, int n) {
    int v = mode ? idx[2 * pos] : idx[pos];
    return v < 0 ? 0 : (v >= n ? n - 1 : v);
}

__device__ __forceinline__ float load_f(const void* p, size_t i, int bf) {
    return bf ? b2f(((const ushort*)p)[i]) : ((const float*)p)[i];
}

// ---------------------------------------------------------------------------
// K1: Q (separate) and KV-interleaved = x @ {Wq,Wk,Wv}.
// KV[node] = [K 32ch | V 32ch] ushorts = one 128-B block per node.
// ---------------------------------------------------------------------------
__global__ void __launch_bounds__(256)
qkv_kernel(const void* __restrict__ x_, const void* __restrict__ Wq_,
           const void* __restrict__ Wk_, const void* __restrict__ Wv_,
           int N, ushort* __restrict__ Q, ushort* __restrict__ KV,
           const int* __restrict__ flags) {
    const int bf = flags[1];
    __shared__ float sW[3][DIM * DIM];
    __shared__ float sx[8][DIM];

    const int tid = threadIdx.x;
    for (int i = tid; i < DIM * DIM; i += 256) {
        sW[0][i] = load_f(Wq_, i, bf);
        sW[1][i] = load_f(Wk_, i, bf);
        sW[2][i] = load_f(Wv_, i, bf);
    }
    const int lr  = tid >> 5;
    const int d   = tid & 31;
    const int row = blockIdx.x * 8 + lr;
    if (row < N) sx[lr][d] = load_f(x_, (size_t)row * DIM + d, bf);
    __syncthreads();
    if (row >= N) return;

    float aq = 0.f, ak = 0.f, av = 0.f;
#pragma unroll
    for (int k = 0; k < DIM; ++k) {
        const float xk = sx[lr][k];
        aq += xk * sW[0][k * DIM + d];
        ak += xk * sW[1][k * DIM + d];
        av += xk * sW[2][k * DIM + d];
    }
    Q[(size_t)row * DIM + d] = f2b(aq);
    KV[(size_t)row * 64 + d]      = f2b(ak);
    KV[(size_t)row * 64 + 32 + d] = f2b(av);
}

// ---------------------------------------------------------------------------
// K2: per-block bucket histogram -> hmat[block][bucket]; global bcount via
// one atomic per nonzero bucket per block.
// ---------------------------------------------------------------------------
__global__ void __launch_bounds__(256)
bin_count_kernel(const int* __restrict__ idx, int E, int N, int nb,
                 int* __restrict__ bcount, int* __restrict__ hmat,
                 const int* __restrict__ flags) {
    const int mode = flags[0];
    __shared__ int h[NBMAX];
    const int tid = threadIdx.x;
    for (int i = tid; i < nb; i += 256) h[i] = 0;
    __syncthreads();
    const int base_e = blockIdx.x * EPB;
#pragma unroll 4
    for (int k = 0; k < 64; ++k) {
        const int e = base_e + k * 256 + tid;
        if (e < E) {
            const int r = load_idx(idx, (size_t)E + e, mode, N);
            atomicAdd(&h[r >> 7], 1);
        }
    }
    __syncthreads();
    int* hrow = hmat + (size_t)blockIdx.x * NBMAX;
    for (int i = tid; i < nb; i += 256) {
        const int v = h[i];
        hrow[i] = v;
        if (v) atomicAdd(&bcount[i], v);
    }
}

// ---------------------------------------------------------------------------
// K3: exclusive scan of bcount[nb] -> bbase. One wave, chunked.
// ---------------------------------------------------------------------------
__global__ void __launch_bounds__(64)
bucket_scan_kernel(const int* __restrict__ bcount, int* __restrict__ bbase,
                   int nb) {
    __shared__ int sRun;
    const int tid = threadIdx.x;
    if (tid == 0) sRun = 0;
    __syncthreads();
    for (int start = 0; start < nb; start += 64) {
        const int ii = start + tid;
        const int v = (ii < nb) ? bcount[ii] : 0;
        int x = v;
#pragma unroll
        for (int off = 1; off < 64; off <<= 1) {
            int t2 = __shfl_up(x, off);
            if (tid >= off) x += t2;
        }
        const int run = sRun;
        __syncthreads();
        if (ii < nb) bbase[ii] = run + x - v;
        if (tid == 63) sRun = run + x;
        __syncthreads();
    }
}

// ---------------------------------------------------------------------------
// K4: per-bucket column scan of hmat (in place): hmat[t][k] becomes the
// global write offset for block t's edges of bucket k. One block per bucket.
// ---------------------------------------------------------------------------
__global__ void __launch_bounds__(64)
bucket_offsets_kernel(int* __restrict__ hmat, const int* __restrict__ bbase,
                      int nblocks, int nb) {
    const int k    = blockIdx.x;
    const int lane = threadIdx.x;
    int run = bbase[k];
    for (int t0 = 0; t0 < nblocks; t0 += 64) {
        const int t = t0 + lane;
        const int v = (t < nblocks) ? hmat[(size_t)t * NBMAX + k] : 0;
        int x = v;
#pragma unroll
        for (int off = 1; off < 64; off <<= 1) {
            int y = __shfl_up(x, off);
            if (lane >= off) x += y;
        }
        if (t < nblocks) hmat[(size_t)t * NBMAX + k] = run + x - v;
        run += __shfl(x, 63);
    }
}

// ---------------------------------------------------------------------------
// K5: single-pass placement. LDS cursors seeded from this block's hmat row;
// no global atomics, no re-histogram. Packed edge = s | r_local<<17.
// ---------------------------------------------------------------------------
__global__ void __launch_bounds__(256)
bin_place_kernel(const int* __restrict__ idx, int E, int N, int nb,
                 const int* __restrict__ hmat, int* __restrict__ bedges,
                 const int* __restrict__ flags) {
    const int mode = flags[0];
    __shared__ int cur[NBMAX];
    const int tid = threadIdx.x;
    const int* hrow = hmat + (size_t)blockIdx.x * NBMAX;
    for (int i = tid; i < nb; i += 256) cur[i] = hrow[i];
    __syncthreads();
    const int base_e = blockIdx.x * EPB;
#pragma unroll 4
    for (int k = 0; k < 64; ++k) {
        const int e = base_e + k * 256 + tid;
        if (e < E) {
            const int r = load_idx(idx, (size_t)E + e, mode, N);
            const int s = load_idx(idx, (size_t)e, mode, N);
            const int b = r >> 7;
            const int p = atomicAdd(&cur[b], 1);
            bedges[p] = s | ((r & 127) << 17);
        }
    }
}

// ---------------------------------------------------------------------------
// K6: per-bucket LDS counting sort -> receiver-sorted sender ids in bedges
// + per-receiver rbase/rcount. One block per bucket.
// ---------------------------------------------------------------------------
__global__ void __launch_bounds__(256)
bucket_sort_kernel(const int* __restrict__ bcount, const int* __restrict__ bbase,
                   int* __restrict__ bedges, int* __restrict__ rbase,
                   int* __restrict__ rcount, int N) {
    __shared__ int eL[SORT_CAP];
    __shared__ int h[RPB];
    __shared__ int off[RPB];
    __shared__ int cur[RPB];

    const int tid = threadIdx.x;
    const int b   = blockIdx.x;
    const int s0  = bbase[b];
    int cnt = bcount[b];
    if (cnt > SORT_CAP) cnt = SORT_CAP;   // statistically unreachable
    const int r0 = b * RPB;
    const int nr = min(RPB, N - r0);

    for (int i = tid; i < RPB; i += 256) h[i] = 0;
    __syncthreads();
    for (int i = tid; i < cnt; i += 256) {
        const int e = bedges[s0 + i];
        eL[i] = e;
        atomicAdd(&h[(e >> 17) & 127], 1);
    }
    __syncthreads();
    if (tid == 0) {
        int a = 0;
        for (int k = 0; k < RPB; ++k) { off[k] = a; a += h[k]; }
    }
    __syncthreads();
    for (int i = tid; i < nr; i += 256) {
        rbase[r0 + i]  = s0 + off[i];
        rcount[r0 + i] = h[i];
        cur[i] = off[i];
    }
    __syncthreads();
    for (int i = tid; i < cnt; i += 256) {
        const int e  = eL[i];
        const int rl = (e >> 17) & 127;
        const int p  = atomicAdd(&cur[rl], 1);
        bedges[s0 + p] = e & 0x1FFFF;
    }
}

// ---------------------------------------------------------------------------
// K7: wave-per-receiver aggregation over KV-interleaved rows.
// 64 lanes = 8 edges x 8 channel-groups; K and V ushort4s come from the SAME
// 128-B KV block per sender. Fused normalize + @Wo + residual.
// ---------------------------------------------------------------------------
__global__ void __launch_bounds__(256)
agg_kernel(const ushort* __restrict__ Q, const ushort* __restrict__ KV,
           const int* __restrict__ slots, const int* __restrict__ rbase,
           const int* __restrict__ rcount, const void* __restrict__ x_,
           const void* __restrict__ Wo_, int N, float* __restrict__ out,
           const int* __restrict__ flags) {
    const int bf = flags[1];
    __shared__ float sWo[DIM * DIM];
    __shared__ float shH[4][DIM];

    const int tid = threadIdx.x;
    for (int i2 = tid; i2 < DIM * DIM; i2 += 256) sWo[i2] = load_f(Wo_, i2, bf);

    const int w    = tid >> 6;
    const int lane = tid & 63;
    const int i    = lane >> 3;    // edge sub-slot 0..7
    const int j    = lane & 7;     // channel group 0..7
    const int r    = blockIdx.x * 4 + w;

    float ax = 0.f, ay = 0.f, azc = 0.f, aw = 0.f;
    float zsum = 0.f;
    float q0 = 0.f, q1 = 0.f, q2 = 0.f, q3 = 0.f;
    int deg = 0, b0 = 0;

    if (r < N) {
        deg = rcount[r];
        b0  = rbase[r];
        const ushort4 qh = *(const ushort4*)(Q + (size_t)r * DIM + j * 4);
        q0 = b2f(qh.x); q1 = b2f(qh.y); q2 = b2f(qh.z); q3 = b2f(qh.w);
    }

    const int chunks = (deg + 7) >> 3;
    for (int cc = 0; cc < chunks; ++cc) {
        const int c   = cc * 8 + i;
        const bool ok = (c < deg);
        const int  s  = slots[b0 + (ok ? c : deg - 1)];
        const ushort* kvrow = KV + (size_t)s * 64;

        const ushort4 kh = *(const ushort4*)(kvrow + j * 4);
        float p = q0 * b2f(kh.x) + q1 * b2f(kh.y) + q2 * b2f(kh.z) + q3 * b2f(kh.w);
        p += __shfl_xor(p, 1);
        p += __shfl_xor(p, 2);
        p += __shfl_xor(p, 4);

        float sc = p * 0.17677669529663687f;   // 1/sqrt(32)
        sc = fminf(fmaxf(sc, -60.f), 60.f);
        const float a = ok ? __expf(sc) : 0.f;

        const ushort4 vh = *(const ushort4*)(kvrow + 32 + j * 4);
        ax  += a * b2f(vh.x); ay += a * b2f(vh.y);
        azc += a * b2f(vh.z); aw += a * b2f(vh.w);
        zsum += a;
    }

#pragma unroll
    for (int off = 8; off < 64; off <<= 1) {
        ax   += __shfl_xor(ax,  off);
        ay   += __shfl_xor(ay,  off);
        azc  += __shfl_xor(azc, off);
        aw   += __shfl_xor(aw,  off);
        zsum += __shfl_xor(zsum, off);
    }

    if (r < N && i == 0) {
        shH[w][j * 4 + 0] = ax;
        shH[w][j * 4 + 1] = ay;
        shH[w][j * 4 + 2] = azc;
        shH[w][j * 4 + 3] = aw;
    }
    __syncthreads();

    if (r < N && lane < DIM) {
        const float inv = 1.f / (zsum + 1e-6f);
        float o = 0.f;
#pragma unroll
        for (int k = 0; k < DIM; ++k) o += shH[w][k] * sWo[k * DIM + lane];
        const size_t oi = (size_t)r * DIM + lane;
        out[oi] = load_f(x_, oi, bf) + inv * o;
    }
}

// ---------------------------------------------------------------------------
extern "C" void kernel_launch(void* const* d_in, const int* in_sizes, int n_in,
                              void* d_out, int out_size, void* d_ws, size_t ws_size,
                              hipStream_t stream) {
    const void* x   = d_in[0];
    const int*  idx = (const int*)d_in[1];
    const void* Wq  = d_in[2];
    const void* Wk  = d_in[3];
    const void* Wv  = d_in[4];
    const void* Wo  = d_in[5];
    float* out = (float*)d_out;           // fp32 reference output

    const int N = in_sizes[0] / DIM;      // 100000
    const int E = in_sizes[1] / 2;        // 1600000
    const int nb = (N + RPB - 1) / RPB;   // 782 buckets
    const int bin_blocks = (E + EPB - 1) / EPB;   // 98
    const size_t N32 = (size_t)N * DIM;

    // Workspace (~27 MB): Q bf16 | KV bf16 (interleaved) | bedges | hmat |
    //                     bcount | bbase | rbase | rcount | flags
    ushort* Q      = (ushort*)d_ws;
    ushort* KV     = Q + N32;                 // N * 64 ushorts (128 B/node)
    int* bedges    = (int*)(KV + (size_t)N * 64);
    int* hmat      = bedges + E;              // bin_blocks * NBMAX
    int* bcount    = hmat + (size_t)bin_blocks * NBMAX;
    int* bbase     = bcount + NBMAX;
    int* rbase     = bbase + NBMAX;
    int* rcount    = rbase + N;
    int* flags     = rcount + N;

    probe_kernel<<<1, 64, 0, stream>>>((const ushort*)x, idx, flags);
    hipMemsetAsync(bcount, 0, NBMAX * sizeof(int), stream);

    qkv_kernel<<<(N + 7) / 8, 256, 0, stream>>>(x, Wq, Wk, Wv, N, Q, KV, flags);

    bin_count_kernel<<<bin_blocks, 256, 0, stream>>>(idx, E, N, nb, bcount,
                                                     hmat, flags);
    bucket_scan_kernel<<<1, 64, 0, stream>>>(bcount, bbase, nb);
    bucket_offsets_kernel<<<nb, 64, 0, stream>>>(hmat, bbase, bin_blocks, nb);
    bin_place_kernel<<<bin_blocks, 256, 0, stream>>>(idx, E, N, nb, hmat,
                                                     bedges, flags);
    bucket_sort_kernel<<<nb, 256, 0, stream>>>(bcount, bbase, bedges,
                                               rbase, rcount, N);

    agg_kernel<<<(N + 3) / 4, 256, 0, stream>>>(Q, KV, bedges, rbase, rcount,
                                                x, Wo, N, out, flags);
}

// Round 8
// 253.435 us; speedup vs baseline: 2.2777x; 1.1007x over previous
//
#include <hip/hip_runtime.h>
#include <hip/hip_bf16.h>

#define DIM 32
#define RPB 32             // receivers per bucket (r_local = 5 bits)
#define NBMAX 4096         // supports N <= 131072
#define SORT_CAP 1024      // bucket edge cap; lambda=512, 22-sigma headroom
#define EPB (256 * 64)     // edges per binning block

// ---------------- f16 / bf16 <-> fp32 helpers ------------------------------
__device__ __forceinline__ float b2f(ushort h) {
    union { float f; unsigned u; } u; u.u = ((unsigned)h) << 16; return u.f;
}
__device__ __forceinline__ float h2f(ushort u) {
    _Float16 h; __builtin_memcpy(&h, &u, 2); return (float)h;
}
__device__ __forceinline__ ushort f2h(float f) {
    _Float16 h = (_Float16)f; ushort u; __builtin_memcpy(&u, &h, 2); return u;
}

// ---------------------------------------------------------------------------
// Probe + init: flags[0] = idx layout (0=int32, 1=int64 low-words),
// flags[1] = x dtype (1=bf16, 0=fp32). Also zeroes bcount (saves a memset
// launch).
// ---------------------------------------------------------------------------
__global__ void __launch_bounds__(256)
probe_init_kernel(const ushort* __restrict__ xh, const int* __restrict__ idx,
                  int* __restrict__ flags, int* __restrict__ bcount) {
    const int tid = threadIdx.x;
    for (int i = tid; i < NBMAX; i += 256) bcount[i] = 0;
    if (tid == 0) {
        int cnt = 0;
        for (int i = 0; i < 128; ++i) {
            int e = (xh[2 * i] >> 7) & 0xFF;
            if (e >= 100 && e <= 135) ++cnt;
        }
        flags[1] = (cnt >= 100) ? 1 : 0;
        int odd_nonzero = 0;
        for (int i = 1; i < 256; i += 2) odd_nonzero += (idx[i] != 0) ? 1 : 0;
        flags[0] = (odd_nonzero == 0) ? 1 : 0;
    }
}

__device__ __forceinline__ int load_idx(const int* __restrict__ idx, size_t pos,
                                        int mode, int n) {
    int v = mode ? idx[2 * pos] : idx[pos];
    return v < 0 ? 0 : (v >= n ? n - 1 : v);
}

__device__ __forceinline__ float load_f(const void* p, size_t i, int bf) {
    return bf ? b2f(((const ushort*)p)[i]) : ((const float*)p)[i];
}

// ---------------------------------------------------------------------------
// K1: Q (f16) and KV-interleaved (f16, [K 32ch | V 32ch] = 128 B/node).
// ---------------------------------------------------------------------------
__global__ void __launch_bounds__(256)
qkv_kernel(const void* __restrict__ x_, const void* __restrict__ Wq_,
           const void* __restrict__ Wk_, const void* __restrict__ Wv_,
           int N, ushort* __restrict__ Q, ushort* __restrict__ KV,
           const int* __restrict__ flags) {
    const int bf = flags[1];
    __shared__ float sW[3][DIM * DIM];
    __shared__ float sx[8][DIM];

    const int tid = threadIdx.x;
    for (int i = tid; i < DIM * DIM; i += 256) {
        sW[0][i] = load_f(Wq_, i, bf);
        sW[1][i] = load_f(Wk_, i, bf);
        sW[2][i] = load_f(Wv_, i, bf);
    }
    const int lr  = tid >> 5;
    const int d   = tid & 31;
    const int row = blockIdx.x * 8 + lr;
    if (row < N) sx[lr][d] = load_f(x_, (size_t)row * DIM + d, bf);
    __syncthreads();
    if (row >= N) return;

    float aq = 0.f, ak = 0.f, av = 0.f;
#pragma unroll
    for (int k = 0; k < DIM; ++k) {
        const float xk = sx[lr][k];
        aq += xk * sW[0][k * DIM + d];
        ak += xk * sW[1][k * DIM + d];
        av += xk * sW[2][k * DIM + d];
    }
    Q[(size_t)row * DIM + d]      = f2h(aq);
    KV[(size_t)row * 64 + d]      = f2h(ak);
    KV[(size_t)row * 64 + 32 + d] = f2h(av);
}

// ---------------------------------------------------------------------------
// K2: per-block bucket histogram -> hmat[block][bucket] + global bcount.
// ---------------------------------------------------------------------------
__global__ void __launch_bounds__(256)
bin_count_kernel(const int* __restrict__ idx, int E, int N, int nb,
                 int* __restrict__ bcount, int* __restrict__ hmat,
                 const int* __restrict__ flags) {
    const int mode = flags[0];
    __shared__ int h[NBMAX];
    const int tid = threadIdx.x;
    for (int i = tid; i < nb; i += 256) h[i] = 0;
    __syncthreads();
    const int base_e = blockIdx.x * EPB;
#pragma unroll 4
    for (int k = 0; k < 64; ++k) {
        const int e = base_e + k * 256 + tid;
        if (e < E) {
            const int r = load_idx(idx, (size_t)E + e, mode, N);
            atomicAdd(&h[r >> 5], 1);
        }
    }
    __syncthreads();
    int* hrow = hmat + (size_t)blockIdx.x * NBMAX;
    for (int i = tid; i < nb; i += 256) {
        const int v = h[i];
        hrow[i] = v;
        if (v) atomicAdd(&bcount[i], v);
    }
}

// ---------------------------------------------------------------------------
// K3: one block (1 wave) per bucket: compute bucket base = prefix(bcount),
// write bbase, then exclusive-scan this bucket's hmat column in place.
// ---------------------------------------------------------------------------
__global__ void __launch_bounds__(64)
offsets_kernel(const int* __restrict__ bcount, int* __restrict__ bbase,
               int* __restrict__ hmat, int nblocks, int nb) {
    const int k    = blockIdx.x;
    const int lane = threadIdx.x;
    // base = sum of bcount[0..k-1]
    int part = 0;
    for (int t = lane; t < k; t += 64) part += bcount[t];
#pragma unroll
    for (int off = 1; off < 64; off <<= 1) part += __shfl_xor(part, off);
    int run = part;
    if (lane == 0) bbase[k] = run;
    // column scan
    for (int t0 = 0; t0 < nblocks; t0 += 64) {
        const int t = t0 + lane;
        const int v = (t < nblocks) ? hmat[(size_t)t * NBMAX + k] : 0;
        int x = v;
#pragma unroll
        for (int off = 1; off < 64; off <<= 1) {
            int y = __shfl_up(x, off);
            if (lane >= off) x += y;
        }
        if (t < nblocks) hmat[(size_t)t * NBMAX + k] = run + x - v;
        run += __shfl(x, 63);
    }
}

// ---------------------------------------------------------------------------
// K4: single-pass placement; LDS cursors seeded from this block's hmat row.
// Packed edge = s | r_local<<17 (s < 2^17, r_local < 32).
// ---------------------------------------------------------------------------
__global__ void __launch_bounds__(256)
bin_place_kernel(const int* __restrict__ idx, int E, int N, int nb,
                 const int* __restrict__ hmat, int* __restrict__ bedges,
                 const int* __restrict__ flags) {
    const int mode = flags[0];
    __shared__ int cur[NBMAX];
    const int tid = threadIdx.x;
    const int* hrow = hmat + (size_t)blockIdx.x * NBMAX;
    for (int i = tid; i < nb; i += 256) cur[i] = hrow[i];
    __syncthreads();
    const int base_e = blockIdx.x * EPB;
#pragma unroll 4
    for (int k = 0; k < 64; ++k) {
        const int e = base_e + k * 256 + tid;
        if (e < E) {
            const int r = load_idx(idx, (size_t)E + e, mode, N);
            const int s = load_idx(idx, (size_t)e, mode, N);
            const int b = r >> 5;
            const int p = atomicAdd(&cur[b], 1);
            bedges[p] = s | ((r & 31) << 17);
        }
    }
}

// ---------------------------------------------------------------------------
// K5 (fused sort + aggregate): one block per bucket of 32 receivers.
//  - stage & counting-sort the bucket's edges in LDS (by r_local)
//  - wave-per-receiver aggregation (8 edges x 8 channel-groups per wave),
//    KV gathers f16 -> v_fma_mix dot, exp, online accumulate in registers
//  - block-wide epilogue: normalize + @Wo + residual, coalesced store
// ---------------------------------------------------------------------------
__global__ void __launch_bounds__(256)
sortagg_kernel(const ushort* __restrict__ Q, const ushort* __restrict__ KV,
               const int* __restrict__ bedges, const int* __restrict__ bcount,
               const int* __restrict__ bbase, const void* __restrict__ x_,
               const void* __restrict__ Wo_, int N, float* __restrict__ out,
               const int* __restrict__ flags) {
    const int bf = flags[1];
    __shared__ int   eL[SORT_CAP];
    __shared__ int   eS[SORT_CAP];
    __shared__ int   h[RPB], off[RPB], cur[RPB];
    __shared__ float accS[RPB][DIM + 1];
    __shared__ float Zs[RPB];
    __shared__ float sWo[DIM * DIM];
    __shared__ ushort sQ[RPB * DIM];

    const int tid = threadIdx.x;
    const int b   = blockIdx.x;
    const int r0  = b * RPB;
    const int nr  = min(RPB, N - r0);
    const int s0  = bbase[b];
    int cnt = min(bcount[b], SORT_CAP);

    for (int i = tid; i < DIM * DIM; i += 256) sWo[i] = load_f(Wo_, i, bf);
    if (tid < RPB) h[tid] = 0;
    for (int i = tid; i < nr * DIM; i += 256) sQ[i] = Q[(size_t)r0 * DIM + i];
    __syncthreads();

    for (int i = tid; i < cnt; i += 256) {
        const int e = bedges[s0 + i];
        eL[i] = e;
        atomicAdd(&h[(e >> 17) & 31], 1);
    }
    __syncthreads();
    if (tid == 0) {
        int a = 0;
#pragma unroll
        for (int k = 0; k < RPB; ++k) { off[k] = a; cur[k] = a; a += h[k]; }
    }
    __syncthreads();
    for (int i = tid; i < cnt; i += 256) {
        const int e  = eL[i];
        const int rl = (e >> 17) & 31;
        const int p  = atomicAdd(&cur[rl], 1);
        eS[p] = e & 0x1FFFF;
    }
    __syncthreads();

    // wave-per-receiver aggregation: wave w handles receivers w, w+4, ...
    const int w    = tid >> 6;
    const int lane = tid & 63;
    const int i8   = lane >> 3;   // edge sub-slot 0..7
    const int j    = lane & 7;    // channel group 0..7

    for (int rl = w; rl < nr; rl += 4) {
        const int deg = h[rl];
        const int o0  = off[rl];
        const ushort4 qh = *(const ushort4*)(sQ + rl * DIM + j * 4);
        const float q0 = h2f(qh.x), q1 = h2f(qh.y), q2 = h2f(qh.z), q3 = h2f(qh.w);

        float ax = 0.f, ay = 0.f, az = 0.f, aw = 0.f, zsum = 0.f;
        const int chunks = (deg + 7) >> 3;
        for (int cc = 0; cc < chunks; ++cc) {
            const int c   = cc * 8 + i8;
            const bool ok = (c < deg);
            const int  s  = eS[o0 + (ok ? c : deg - 1)];
            const ushort* kvrow = KV + (size_t)s * 64;

            const ushort4 kh = *(const ushort4*)(kvrow + j * 4);
            float p = h2f(kh.x) * q0;
            p = fmaf(h2f(kh.y), q1, p);
            p = fmaf(h2f(kh.z), q2, p);
            p = fmaf(h2f(kh.w), q3, p);
            p += __shfl_xor(p, 1);
            p += __shfl_xor(p, 2);
            p += __shfl_xor(p, 4);

            float sc = p * 0.17677669529663687f;   // 1/sqrt(32)
            sc = fminf(fmaxf(sc, -60.f), 60.f);
            const float a = ok ? __expf(sc) : 0.f;

            const ushort4 vh = *(const ushort4*)(kvrow + 32 + j * 4);
            ax = fmaf(h2f(vh.x), a, ax);
            ay = fmaf(h2f(vh.y), a, ay);
            az = fmaf(h2f(vh.z), a, az);
            aw = fmaf(h2f(vh.w), a, aw);
            zsum += a;
        }
#pragma unroll
        for (int o = 8; o < 64; o <<= 1) {
            ax += __shfl_xor(ax, o);
            ay += __shfl_xor(ay, o);
            az += __shfl_xor(az, o);
            aw += __shfl_xor(aw, o);
            zsum += __shfl_xor(zsum, o);
        }
        if (i8 == 0) {
            accS[rl][j * 4 + 0] = ax;
            accS[rl][j * 4 + 1] = ay;
            accS[rl][j * 4 + 2] = az;
            accS[rl][j * 4 + 3] = aw;
            if (j == 0) Zs[rl] = zsum;
        }
    }
    __syncthreads();

    // epilogue: 256 threads = 8 rows x 32 cols, 4 iterations covers 32 rows
    const int lr = tid >> 5;
    const int d  = tid & 31;
#pragma unroll
    for (int it = 0; it < RPB / 8; ++it) {
        const int rl = it * 8 + lr;
        if (rl < nr) {
            const float inv = 1.f / (Zs[rl] + 1e-6f);
            float o = 0.f;
#pragma unroll
            for (int k = 0; k < DIM; ++k) o += accS[rl][k] * sWo[k * DIM + d];
            const size_t oi = (size_t)(r0 + rl) * DIM + d;
            out[oi] = load_f(x_, oi, bf) + inv * o;
        }
    }
}

// ---------------------------------------------------------------------------
extern "C" void kernel_launch(void* const* d_in, const int* in_sizes, int n_in,
                              void* d_out, int out_size, void* d_ws, size_t ws_size,
                              hipStream_t stream) {
    const void* x   = d_in[0];
    const int*  idx = (const int*)d_in[1];
    const void* Wq  = d_in[2];
    const void* Wk  = d_in[3];
    const void* Wv  = d_in[4];
    const void* Wo  = d_in[5];
    float* out = (float*)d_out;           // fp32 reference output

    const int N = in_sizes[0] / DIM;      // 100000
    const int E = in_sizes[1] / 2;        // 1600000
    const int nb = (N + RPB - 1) / RPB;   // 3125 buckets
    const int bin_blocks = (E + EPB - 1) / EPB;   // 98
    const size_t N32 = (size_t)N * DIM;

    // Workspace (~27 MB): Q f16 | KV f16 | bedges | hmat | bcount | bbase | flags
    ushort* Q      = (ushort*)d_ws;
    ushort* KV     = Q + N32;                 // N * 64 halves (128 B/node)
    int* bedges    = (int*)(KV + (size_t)N * 64);
    int* hmat      = bedges + E;              // bin_blocks * NBMAX
    int* bcount    = hmat + (size_t)bin_blocks * NBMAX;
    int* bbase     = bcount + NBMAX;
    int* flags     = bbase + NBMAX;

    probe_init_kernel<<<1, 256, 0, stream>>>((const ushort*)x, idx, flags, bcount);

    qkv_kernel<<<(N + 7) / 8, 256, 0, stream>>>(x, Wq, Wk, Wv, N, Q, KV, flags);

    bin_count_kernel<<<bin_blocks, 256, 0, stream>>>(idx, E, N, nb, bcount,
                                                     hmat, flags);
    offsets_kernel<<<nb, 64, 0, stream>>>(bcount, bbase, hmat, bin_blocks, nb);
    bin_place_kernel<<<bin_blocks, 256, 0, stream>>>(idx, E, N, nb, hmat,
                                                     bedges, flags);

    sortagg_kernel<<<nb, 256, 0, stream>>>(Q, KV, bedges, bcount, bbase,
                                           x, Wo, N, out, flags);
}